// Round 15
// baseline (386.578 us; speedup 1.0000x reference)
//
#include <hip/hip_runtime.h>

typedef __attribute__((ext_vector_type(8))) short short8;
typedef __attribute__((ext_vector_type(4))) float f32x4;
typedef __attribute__((ext_vector_type(4))) unsigned short us4;
typedef __attribute__((ext_vector_type(4))) float float4v;

#define GLB_PTR(p) ((const __attribute__((address_space(1))) void*)(p))
#define LDS_PTR(p) ((__attribute__((address_space(3))) void*)(p))

__device__ __forceinline__ unsigned short f2bf(float f) {
  unsigned int u = __float_as_uint(f);
  u += 0x7FFF + ((u >> 16) & 1);   // round-to-nearest-even
  return (unsigned short)(u >> 16);
}

// ---------------- all fp32 -> bf16 converts, ONE flattened grid-stride range ----------------
__global__ void cvt_all(const float* __restrict__ i0, const float* __restrict__ i1,
                        const float* __restrict__ i2, const float* __restrict__ i3,
                        const float* __restrict__ i4, const float* __restrict__ i5,
                        unsigned short* __restrict__ o0, unsigned short* __restrict__ o1,
                        unsigned short* __restrict__ o2, unsigned short* __restrict__ o3,
                        unsigned short* __restrict__ o4, unsigned short* __restrict__ o5) {
  constexpr int N0 = 16384 * 1536 / 4, N1 = 616 * 1536 / 4, NW = 1536 * 1536 / 4;
  constexpr int TOT = N0 + N1 + 4 * NW;
  int i = blockIdx.x * blockDim.x + threadIdx.x;
  const int stride = gridDim.x * blockDim.x;
  for (; i < TOT; i += stride) {
    const float* in; unsigned short* out; int j = i;
    if (j < N0)              { in = i0; out = o0; }
    else if ((j -= N0) < N1) { in = i1; out = o1; }
    else {
      j -= N1;
      const int t = j / NW; j -= t * NW;
      in  = t == 0 ? i2 : t == 1 ? i3 : t == 2 ? i4 : i5;
      out = t == 0 ? o2 : t == 1 ? o3 : t == 2 ? o4 : o5;
    }
    float4v v = *(const float4v*)(in + (size_t)j * 4);
    us4 o;
    o[0] = f2bf(v[0]); o[1] = f2bf(v[1]); o[2] = f2bf(v[2]); o[3] = f2bf(v[3]);
    *(us4*)(out + (size_t)j * 4) = o;
  }
}

// ---------------- big bf16 GEMM body: C[16384,1536] = A[16384,1536] * B[1536,1536]^T ------------
// 128x128 tile, BK=32, 8 waves (4M x 2N), wave tile 32x64 (acc[2][4]=32 VGPR).
// 3 LDS buffers, prefetch distance 2 -> ONE barrier per K-tile:
//   iter kt: vmcnt(2) [own stage(kt) retired] -> BAR [all waves' stage(kt) retired] ->
//            read frags(buf kt%3) + stage(kt+2 -> buf (kt+2)%3 == (kt-1)%3, whose readers
//            all drained before THIS barrier) -> lgkm0 -> MFMA.
// 48 KB LDS -> 3 blocks/CU (24 waves/CU); grid 1536 = exactly 2 fills; XCD swizzle (1536%8=0).
// Swizzle: LDS[row][g] holds global granule g^(row&3), both sides (involution).
// MODE 0: C bf16. MODE 1: C fp32 = acc + bias[n] + resid[m,n].
template<int MODE>
__device__ __forceinline__ void gemm_big_body(
    const unsigned short* __restrict__ A,
    const unsigned short* __restrict__ B,
    unsigned short* __restrict__ Cb,
    float* __restrict__ Cf,
    const float* __restrict__ bias,
    const float* __restrict__ resid,
    unsigned short* smem, int bid, int tid) {
  constexpr int K = 1536, N = 1536, BK = 32, NKT = K / BK;  // 48 K-tiles
  unsigned short* As = smem;              // 3 x 128x32
  unsigned short* Bs = smem + 3 * 4096;   // 3 x 128x32

  // XCD-chunked: 1536 blocks -> 192/XCD = 16 m-tiles x 12 n-tiles, n fastest
  const int xcd = bid & 7, idx = bid >> 3;
  const int m0 = (xcd * 16 + idx / 12) * 128;
  const int n0 = (idx % 12) * 128;

  const int w = tid >> 6, l = tid & 63, lr = l & 15, lg = l >> 4;
  const int wr = w >> 1, wc = w & 1;               // 4M x 2N wave grid
  const int ga = lg ^ (lr & 3);                    // swizzled read granule

  const int srow = w * 16 + (l >> 2);              // staging row 0..127
  const int sg = (l & 3) ^ ((l >> 2) & 3);         // pre-swizzled source granule (row&3==(l>>2)&3)
  const unsigned short* aSrc = A + (size_t)(m0 + srow) * K + sg * 8;
  const unsigned short* bSrc = B + (size_t)(n0 + srow) * K + sg * 8;

  f32x4 acc[2][4] = {};

  auto stage = [&](int buf, int kt) {              // 2 loads/wave
    const int k0 = kt * BK;
    __builtin_amdgcn_global_load_lds(GLB_PTR(aSrc + k0), LDS_PTR(As + buf * 4096 + w * 512), 16, 0, 0);
    __builtin_amdgcn_global_load_lds(GLB_PTR(bSrc + k0), LDS_PTR(Bs + buf * 4096 + w * 512), 16, 0, 0);
  };

  auto loadfrags = [&](int buf, short8* af, short8* bfv) {
    const unsigned short* Asb = As + buf * 4096;
    const unsigned short* Bsb = Bs + buf * 4096;
#pragma unroll
    for (int i = 0; i < 2; ++i)
      af[i] = *(const short8*)(Asb + (wr * 32 + i * 16 + lr) * 32 + ga * 8);
#pragma unroll
    for (int j = 0; j < 4; ++j)
      bfv[j] = *(const short8*)(Bsb + (wc * 64 + j * 16 + lr) * 32 + ga * 8);
  };

  // prologue: 2 K-tiles in flight (4 loads/wave)
  stage(0, 0); stage(1, 1);

  for (int kt = 0; kt < NKT; ++kt) {
    if (kt < NKT - 1) asm volatile("s_waitcnt vmcnt(2)" ::: "memory");  // own stage(kt) retired
    else              asm volatile("s_waitcnt vmcnt(0)" ::: "memory");
    __builtin_amdgcn_s_barrier();                       // ONE barrier: buf kt%3 valid everywhere
    __builtin_amdgcn_sched_barrier(0);
    short8 af[2], bfv[4];
    loadfrags(kt % 3, af, bfv);
    if (kt + 2 < NKT) stage((kt + 2) % 3, kt + 2);      // == buf (kt-1)%3, drained pre-barrier
    asm volatile("s_waitcnt lgkmcnt(0)" ::: "memory");  // frags in regs
    __builtin_amdgcn_sched_barrier(0);
    __builtin_amdgcn_s_setprio(1);
#pragma unroll
    for (int i = 0; i < 2; ++i)
#pragma unroll
      for (int j = 0; j < 4; ++j)
        acc[i][j] = __builtin_amdgcn_mfma_f32_16x16x32_bf16(af[i], bfv[j], acc[i][j], 0, 0, 0);
    __builtin_amdgcn_s_setprio(0);
  }

#pragma unroll
  for (int i = 0; i < 2; ++i) {
    const int rb = m0 + wr * 32 + i * 16 + lg * 4;
#pragma unroll
    for (int j = 0; j < 4; ++j) {
      const int col = n0 + wc * 64 + j * 16 + lr;
#pragma unroll
      for (int r = 0; r < 4; ++r) {
        size_t o = (size_t)(rb + r) * N + col;
        if (MODE == 0) Cb[o] = f2bf(acc[i][j][r]);
        else           Cf[o] = acc[i][j][r] + bias[col] + resid[o];
      }
    }
  }
}

// ---------------- K+V projection body (waves 0-3 active; waves 4-7 barrier-only) ----------------
__device__ __forceinline__ void gemm_kv_body(
    const unsigned short* __restrict__ A,    // EHSb [616,1536]
    const unsigned short* __restrict__ Bk,
    const unsigned short* __restrict__ Bv,
    unsigned short* __restrict__ Ck,
    unsigned short* __restrict__ Vt,
    unsigned short* smem, int by, int tid) {
  constexpr int K = 1536, N = 1536, Mc = 615;
  unsigned short* As = smem;
  unsigned short* Bs = smem + 4096;
  const int bx = by % 5, yy = by / 5;
  const unsigned short* B = yy < 12 ? Bk : Bv;
  const int m0 = bx * 128, n0 = (yy % 12) * 128;
  const bool act = tid < 256;
  const int t = tid;
  const int w = t >> 6, l = t & 63, lr = l & 15, lg = l >> 4;
  const int wr = w >> 1, wc = w & 1;
  const int srow = t >> 2, scol = (t & 3) * 8;

  f32x4 acc[4][4] = {};
  unsigned short* AsW = As + w * 512;
  unsigned short* BsW = Bs + w * 512;
  long ar0 = m0 + srow;       if (ar0 > Mc) ar0 = Mc;
  long ar1 = m0 + srow + 64;  if (ar1 > Mc) ar1 = Mc;

  for (int k0 = 0; k0 < K; k0 += 32) {
    if (act) {
      __builtin_amdgcn_global_load_lds(GLB_PTR(A + ar0 * (long)K + k0 + scol), LDS_PTR(AsW),        16, 0, 0);
      __builtin_amdgcn_global_load_lds(GLB_PTR(A + ar1 * (long)K + k0 + scol), LDS_PTR(AsW + 2048), 16, 0, 0);
      __builtin_amdgcn_global_load_lds(GLB_PTR(B + (long)(n0 + srow) * K + k0 + scol),      LDS_PTR(BsW),        16, 0, 0);
      __builtin_amdgcn_global_load_lds(GLB_PTR(B + (long)(n0 + srow + 64) * K + k0 + scol), LDS_PTR(BsW + 2048), 16, 0, 0);
    }
    __syncthreads();
    if (act) {
      short8 af[4], bfv[4];
#pragma unroll
      for (int i = 0; i < 4; ++i) {
        af[i]  = *(const short8*)(As + (wr * 64 + i * 16 + lr) * 32 + lg * 8);
        bfv[i] = *(const short8*)(Bs + (wc * 64 + i * 16 + lr) * 32 + lg * 8);
      }
#pragma unroll
      for (int i = 0; i < 4; ++i)
#pragma unroll
        for (int j = 0; j < 4; ++j)
          acc[i][j] = __builtin_amdgcn_mfma_f32_16x16x32_bf16(af[i], bfv[j], acc[i][j], 0, 0, 0);
    }
    __syncthreads();
  }

  if (!act) return;
  if (yy < 12) {
#pragma unroll
    for (int i = 0; i < 4; ++i) {
      int rb = m0 + wr * 64 + i * 16 + lg * 4;
#pragma unroll
      for (int j = 0; j < 4; ++j) {
        int col = n0 + wc * 64 + j * 16 + lr;
#pragma unroll
        for (int r = 0; r < 4; ++r)
          Ck[(long)(rb + r) * N + col] = f2bf(acc[i][j][r]);
      }
    }
  } else {
#pragma unroll
    for (int i = 0; i < 4; ++i) {
      int rb = m0 + wr * 64 + i * 16 + lg * 4;
#pragma unroll
      for (int j = 0; j < 4; ++j) {
        int col = n0 + wc * 64 + j * 16 + lr;
        int hh = col >> 6, dd = col & 63;
#pragma unroll
        for (int r = 0; r < 4; ++r) {
          int m = rb + r;
          if (m < 616) {
            int c = (unsigned)m / 154u;
            int e = m - c * 154;
            Vt[((long)((c * 24 + hh) * 64 + dd)) * 160 + e] = f2bf(acc[i][j][r]);
          }
        }
      }
    }
  }
}

// blocks 0..1535: Q GEMM (exactly 2 fills at 3 blocks/CU); 1536..1655: K/V projection.
__global__ __launch_bounds__(512, 4) void gemm_q_kv(
    const unsigned short* __restrict__ HSb, const unsigned short* __restrict__ Wqb,
    unsigned short* __restrict__ Qb,
    const unsigned short* __restrict__ EHSb, const unsigned short* __restrict__ Wkb,
    const unsigned short* __restrict__ Wvb,
    unsigned short* __restrict__ Ck, unsigned short* __restrict__ Vt) {
  __shared__ unsigned short smem[24576];   // 48 KB
  if (blockIdx.x < 1536)
    gemm_big_body<0>(HSb, Wqb, Qb, nullptr, nullptr, nullptr, smem, blockIdx.x, threadIdx.x);
  else
    gemm_kv_body(EHSb, Wkb, Wvb, Ck, Vt, smem, blockIdx.x - 1536, threadIdx.x);
}

__global__ __launch_bounds__(512, 4) void gemm_o(
    const unsigned short* __restrict__ Ob, const unsigned short* __restrict__ Wob,
    float* __restrict__ Cf, const float* __restrict__ bias, const float* __restrict__ resid) {
  __shared__ unsigned short smem[24576];
  gemm_big_body<1>(Ob, Wob, nullptr, Cf, bias, resid, smem, blockIdx.x, threadIdx.x);
}

// ---------------- fused cross-component attention (incremental PV, 16 KB LDS) ----------------
// Softmax over components is elementwise in e -> PV consumes P per 32-e slice:
// for ks: {qk(2ks), qk(2ks+1) -> P2 slice [c][16][32] -> PV(ks)}. P2 16 KB -> 8 blocks/CU
// (32 waves/CU, was 8). P2 wave-private: no barriers, lgkm drains only. No-max softmax
// (|scores|<<88). P masked 0 for e>=154. Coalesced output via P2 re-use.
__global__ __launch_bounds__(256) void attn_kernel(
    const unsigned short* __restrict__ Qb,   // [4*4096, 1536]
    const unsigned short* __restrict__ Kb,   // [640, 1536]; rows c*154+e (e>=154 junk, masked)
    const unsigned short* __restrict__ Vt,   // [4][24][64][160]; e>=154 junk, masked via P
    const float* __restrict__ temp,
    unsigned short* __restrict__ Ob) {       // [4*4096, 1536]
  __shared__ unsigned short P2[4][4][16][32];  // [wave][c][s][e-local] 16 KB, wave-private
  const int h = blockIdx.y, sb = blockIdx.x;
  const int t = threadIdx.x, w = t >> 6, l = t & 63, lr = l & 15, lg = l >> 4;
  const int s0 = sb * 64 + w * 16;
  const float sc = 1.0f / (temp[0] + 1e-8f);

  short8 qf[4][2];
#pragma unroll
  for (int c = 0; c < 4; ++c)
#pragma unroll
    for (int kt = 0; kt < 2; ++kt)
      qf[c][kt] = *(const short8*)(Qb + (long)(c * 4096 + s0 + lr) * 1536 + h * 64 + kt * 32 + lg * 8);

  short8 kA[4][2], kB[4][2];
  auto loadK = [&](int et, short8 (&k)[4][2]) {
#pragma unroll
    for (int c = 0; c < 4; ++c)
#pragma unroll
      for (int kt = 0; kt < 2; ++kt)
        k[c][kt] = *(const short8*)(Kb + (long)(c * 154 + et * 16 + lr) * 1536 + h * 64 + kt * 32 + lg * 8);
  };

  auto qk_step = [&](int et, short8 (&kc)[4][2], short8 (&kn)[4][2], bool pre) {
    if (pre) loadK(et + 1, kn);               // next-tile K loads fly under the MFMAs
    f32x4 sa[4] = {};
#pragma unroll
    for (int c = 0; c < 4; ++c)
#pragma unroll
      for (int kt = 0; kt < 2; ++kt)
        sa[c] = __builtin_amdgcn_mfma_f32_16x16x32_bf16(kc[c][kt], qf[c][kt], sa[c], 0, 0, 0);
    float wv[4][4];
#pragma unroll
    for (int r = 0; r < 4; ++r) {
      float e0 = __expf(sa[0][r] * sc), e1 = __expf(sa[1][r] * sc);
      float e2 = __expf(sa[2][r] * sc), e3 = __expf(sa[3][r] * sc);
      float inv = 1.0f / (e0 + e1 + e2 + e3);
      wv[0][r] = e0 * inv; wv[1][r] = e1 * inv; wv[2][r] = e2 * inv; wv[3][r] = e3 * inv;
    }
    const int el = (et & 1) * 16 + lg * 4;    // e-local within 32-slice
#pragma unroll
    for (int c = 0; c < 4; ++c) {
      us4 pk;
#pragma unroll
      for (int r = 0; r < 4; ++r)
        pk[r] = (et * 16 + lg * 4 + r < 154) ? f2bf(wv[c][r]) : (unsigned short)0;
      *(us4*)&P2[w][c][lr][el] = pk;
    }
  };

  short8 vA[4], vB[4];
  auto loadV = [&](int c, int ks, short8 (&v)[4]) {
#pragma unroll
    for (int nt = 0; nt < 4; ++nt)
      v[nt] = *(const short8*)(Vt + (long)((c * 24 + h) * 64 + nt * 16 + lr) * 160 + ks * 32 + lg * 8);
  };

  f32x4 o[4][4] = {};
  loadK(0, kA);
  loadV(0, 0, vA);                            // V(c=0, ks=0) prefetched early
#pragma unroll
  for (int ks = 0; ks < 5; ++ks) {
    qk_step(2 * ks,     kA, kB, true);
    qk_step(2 * ks + 1, kB, kA, ks < 4);
    asm volatile("s_waitcnt lgkmcnt(0)" ::: "memory");   // P2 slice writes drained (wave-private)
    __builtin_amdgcn_sched_barrier(0);
#pragma unroll
    for (int c = 0; c < 4; ++c) {
      // prefetch next (c,ks) V into the other buffer (static ping-pong, rule #20)
      if (c == 0)      loadV(1, ks, vB);
      else if (c == 1) loadV(2, ks, vA);
      else if (c == 2) loadV(3, ks, vB);
      else if (ks < 4) loadV(0, ks + 1, vA);
      short8 pf = *(const short8*)&P2[w][c][lr][lg * 8];
      short8* vv = (c & 1) ? vB : vA;
#pragma unroll
      for (int nt = 0; nt < 4; ++nt)
        o[c][nt] = __builtin_amdgcn_mfma_f32_16x16x32_bf16(pf, vv[nt], o[c][nt], 0, 0, 0);
    }
  }

  // ---- coalesced Ob write: stage 16x64 tile in now-free wave-private P2[w] ----
  unsigned short* OS = &P2[w][0][0][0];       // 2048 shorts available, need 1024
#pragma unroll
  for (int c = 0; c < 4; ++c) {
#pragma unroll
    for (int nt = 0; nt < 4; ++nt)
#pragma unroll
      for (int r = 0; r < 4; ++r)
        OS[(lg * 4 + r) * 64 + nt * 16 + lr] = f2bf(o[c][nt][r]);
    asm volatile("s_waitcnt lgkmcnt(0)" ::: "memory");
    __builtin_amdgcn_sched_barrier(0);
#pragma unroll
    for (int p = 0; p < 2; ++p) {
      const int flat = p * 512 + l * 8;
      const int row = flat >> 6, col = flat & 63;
      short8 v = *(const short8*)(OS + flat);
      *(short8*)(Ob + (long)(c * 4096 + s0 + row) * 1536 + h * 64 + col) = v;
    }
  }
}

extern "C" void kernel_launch(void* const* d_in, const int* in_sizes, int n_in,
                              void* d_out, int out_size, void* d_ws, size_t ws_size,
                              hipStream_t stream) {
  (void)in_sizes; (void)n_in; (void)out_size; (void)ws_size;
  const float* HS  = (const float*)d_in[0];
  const float* EHS = (const float*)d_in[1];
  const float* TMP = (const float*)d_in[2];
  const float* Wq  = (const float*)d_in[3];
  const float* Wk  = (const float*)d_in[4];
  const float* Wv  = (const float*)d_in[5];
  const float* Wo  = (const float*)d_in[6];
  const float* bo  = (const float*)d_in[7];

  char* ws = (char*)d_ws;
  size_t off = 0;
  unsigned short* HSb  = (unsigned short*)(ws + off); off += (size_t)16384 * 1536 * 2;  // reused as Ob
  unsigned short* Ob   = HSb;
  unsigned short* EHSb = (unsigned short*)(ws + off); off += (size_t)616 * 1536 * 2;
  unsigned short* Wqb  = (unsigned short*)(ws + off); off += (size_t)1536 * 1536 * 2;
  unsigned short* Wkb  = (unsigned short*)(ws + off); off += (size_t)1536 * 1536 * 2;
  unsigned short* Wvb  = (unsigned short*)(ws + off); off += (size_t)1536 * 1536 * 2;
  unsigned short* Wob  = (unsigned short*)(ws + off); off += (size_t)1536 * 1536 * 2;
  unsigned short* Kb   = (unsigned short*)(ws + off); off += (size_t)640 * 1536 * 2;
  unsigned short* Vt   = (unsigned short*)(ws + off); off += (size_t)4 * 24 * 64 * 160 * 2;
  unsigned short* Qb   = (unsigned short*)d_out;  // bf16 scratch; final GEMM overwrites d_out fully

  cvt_all<<<2048, 256, 0, stream>>>(HS, EHS, Wq, Wk, Wv, Wo,
                                    HSb, EHSb, Wqb, Wkb, Wvb, Wob);

  gemm_q_kv<<<1656, 512, 0, stream>>>(HSb, Wqb, Qb, EHSb, Wkb, Wvb, Kb, Vt);

  attn_kernel<<<dim3(64, 24), 256, 0, stream>>>(Qb, Kb, Vt, TMP, Ob);

  gemm_o<<<1536, 512, 0, stream>>>(Ob, Wob, (float*)d_out, bo, HS);
}

// Round 16
// 353.950 us; speedup vs baseline: 1.0922x; 1.0922x over previous
//
#include <hip/hip_runtime.h>

typedef __attribute__((ext_vector_type(8))) short short8;
typedef __attribute__((ext_vector_type(4))) float f32x4;
typedef __attribute__((ext_vector_type(4))) unsigned short us4;
typedef __attribute__((ext_vector_type(4))) float float4v;

#define GLB_PTR(p) ((const __attribute__((address_space(1))) void*)(p))
#define LDS_PTR(p) ((__attribute__((address_space(3))) void*)(p))

__device__ __forceinline__ unsigned short f2bf(float f) {
  unsigned int u = __float_as_uint(f);
  u += 0x7FFF + ((u >> 16) & 1);   // round-to-nearest-even
  return (unsigned short)(u >> 16);
}

// ---------------- all fp32 -> bf16 converts, ONE flattened grid-stride range ----------------
__global__ void cvt_all(const float* __restrict__ i0, const float* __restrict__ i1,
                        const float* __restrict__ i2, const float* __restrict__ i3,
                        const float* __restrict__ i4, const float* __restrict__ i5,
                        unsigned short* __restrict__ o0, unsigned short* __restrict__ o1,
                        unsigned short* __restrict__ o2, unsigned short* __restrict__ o3,
                        unsigned short* __restrict__ o4, unsigned short* __restrict__ o5) {
  constexpr int N0 = 16384 * 1536 / 4, N1 = 616 * 1536 / 4, NW = 1536 * 1536 / 4;
  constexpr int TOT = N0 + N1 + 4 * NW;   // 8,887,296 x 4-elem groups
  int i = blockIdx.x * blockDim.x + threadIdx.x;
  const int stride = gridDim.x * blockDim.x;
  for (; i < TOT; i += stride) {
    const float* in; unsigned short* out; int j = i;
    if (j < N0)              { in = i0; out = o0; }
    else if ((j -= N0) < N1) { in = i1; out = o1; }
    else {
      j -= N1;
      const int t = j / NW; j -= t * NW;
      in  = t == 0 ? i2 : t == 1 ? i3 : t == 2 ? i4 : i5;
      out = t == 0 ? o2 : t == 1 ? o3 : t == 2 ? o4 : o5;
    }
    float4v v = *(const float4v*)(in + (size_t)j * 4);
    us4 o;
    o[0] = f2bf(v[0]); o[1] = f2bf(v[1]); o[2] = f2bf(v[2]); o[3] = f2bf(v[3]);
    *(us4*)(out + (size_t)j * 4) = o;
  }
}

// ---------------- big bf16 GEMM body: C[16384,1536] = A[16384,1536] * B[1536,1536]^T ------------
// MEASURED-BEST of 9 structure variants (rounds 1-15): 655 TF, 118.5 us steady.
// 256x128 block tile, BK=32, 8 waves (4M x 2N), wave tile 64x64 (acc[4][4]=64 VGPR, no spill).
// DEPTH-2 LDS (48 KB -> 3 blocks/CU LDS-limited; grid 768 = EXACTLY one fill; 6 waves/SIMD).
// Per iter: vmcnt(3) [stage(kt) retired; stage(kt+1)'s 3 loads stay in flight] -> barrier ->
// frag-reads -> lgkm(0) -> barrier -> stage(kt+2) into drained buffer -> MFMA.
// Swizzle: LDS[row][g] holds global granule g^(row&3), both sides (involution).
// MODE 0: C bf16.  MODE 1: C fp32 = acc + bias[n] + resid[m,n].
template<int MODE>
__device__ __forceinline__ void gemm_big_body(
    const unsigned short* __restrict__ A,
    const unsigned short* __restrict__ B,
    unsigned short* __restrict__ Cb,
    float* __restrict__ Cf,
    const float* __restrict__ bias,
    const float* __restrict__ resid,
    unsigned short* smem, int bid, int tid) {
  constexpr int K = 1536, N = 1536, BK = 32, NKT = K / BK;  // 48 K-tiles
  unsigned short* As = smem;             // 2 x 256x32 elems
  unsigned short* Bs = smem + 2 * 8192;  // 2 x 128x32 elems

  // XCD-chunked swizzle: 768 blocks -> 96/XCD = 8 m-tiles x 12 n-tiles, n fastest
  const int xcd = bid & 7, idx = bid >> 3;
  const int m0 = (xcd * 8 + idx / 12) * 256;
  const int n0 = (idx % 12) * 128;

  const int w = tid >> 6, l = tid & 63, lr = l & 15, lg = l >> 4;
  const int wr = w >> 1, wc = w & 1;               // 4M x 2N wave grid
  const int ga = lg ^ (lr & 3);                    // swizzled read granule

  const int srow = w * 16 + (l >> 2);              // staging row 0..127
  const int sg = (l & 3) ^ ((l >> 2) & 3);         // pre-swizzled source granule (involution)
  const unsigned short* aSrc = A + (size_t)(m0 + srow) * K + sg * 8;
  const unsigned short* bSrc = B + (size_t)(n0 + srow) * K + sg * 8;

  f32x4 acc[4][4] = {};

  auto stage = [&](int buf, int kt) {              // 3 loads/wave
    const int k0 = kt * BK;
    unsigned short* AsW = As + buf * 8192 + w * 512;   // wave-uniform base
    unsigned short* BsW = Bs + buf * 4096 + w * 512;
    __builtin_amdgcn_global_load_lds(GLB_PTR(aSrc + k0),                    LDS_PTR(AsW),        16, 0, 0);
    __builtin_amdgcn_global_load_lds(GLB_PTR(aSrc + (size_t)128 * K + k0),  LDS_PTR(AsW + 4096), 16, 0, 0);
    __builtin_amdgcn_global_load_lds(GLB_PTR(bSrc + k0),                    LDS_PTR(BsW),        16, 0, 0);
  };

  auto loadfrags = [&](int buf, short8* af, short8* bfv) {
    const unsigned short* Asb = As + buf * 8192;
    const unsigned short* Bsb = Bs + buf * 4096;
#pragma unroll
    for (int i = 0; i < 4; ++i)
      af[i] = *(const short8*)(Asb + (wr * 64 + i * 16 + lr) * 32 + ga * 8);
#pragma unroll
    for (int j = 0; j < 4; ++j)
      bfv[j] = *(const short8*)(Bsb + (wc * 64 + j * 16 + lr) * 32 + ga * 8);
  };

  auto mfma_all = [&](short8* af, short8* bfv) {
#pragma unroll
    for (int i = 0; i < 4; ++i)
#pragma unroll
      for (int j = 0; j < 4; ++j)
        acc[i][j] = __builtin_amdgcn_mfma_f32_16x16x32_bf16(af[i], bfv[j], acc[i][j], 0, 0, 0);
  };

  // prologue: 2 K-tiles in flight (6 loads/wave)
  stage(0, 0); stage(1, 1);

  for (int kt = 0; kt < NKT; ++kt) {
    if (kt < NKT - 1) asm volatile("s_waitcnt vmcnt(3)" ::: "memory");  // stage(kt) retired
    else              asm volatile("s_waitcnt vmcnt(0)" ::: "memory");
    __builtin_amdgcn_s_barrier();                       // join: buf kt&1 valid everywhere
    __builtin_amdgcn_sched_barrier(0);
    short8 af[4], bfv[4];
    loadfrags(kt & 1, af, bfv);
    asm volatile("s_waitcnt lgkmcnt(0)" ::: "memory");  // frags in regs
    __builtin_amdgcn_sched_barrier(0);
    __builtin_amdgcn_s_barrier();                       // all waves done reading buf kt&1
    __builtin_amdgcn_sched_barrier(0);
    if (kt + 2 < NKT) stage(kt & 1, kt + 2);            // overwrite freed buffer
    __builtin_amdgcn_s_setprio(1);
    mfma_all(af, bfv);
    __builtin_amdgcn_s_setprio(0);
  }

#pragma unroll
  for (int i = 0; i < 4; ++i) {
    const int rb = m0 + wr * 64 + i * 16 + lg * 4;
#pragma unroll
    for (int j = 0; j < 4; ++j) {
      const int col = n0 + wc * 64 + j * 16 + lr;
#pragma unroll
      for (int r = 0; r < 4; ++r) {
        size_t o = (size_t)(rb + r) * N + col;
        if (MODE == 0) Cb[o] = f2bf(acc[i][j][r]);
        else           Cf[o] = acc[i][j][r] + bias[col] + resid[o];
      }
    }
  }
}

// ---------------- K+V projection body (runs in waves 0-3; waves 4-7 barrier-only) ----------------
// yy<12: Ck row-major bf16.  yy>=12: Vt[c][h][d][e(160)] transposed write (e>=154 junk, masked in attn).
__device__ __forceinline__ void gemm_kv_body(
    const unsigned short* __restrict__ A,    // EHSb [616,1536]
    const unsigned short* __restrict__ Bk,
    const unsigned short* __restrict__ Bv,
    unsigned short* __restrict__ Ck,
    unsigned short* __restrict__ Vt,
    unsigned short* smem, int by, int tid) {
  constexpr int K = 1536, N = 1536, Mc = 615;
  unsigned short* As = smem;
  unsigned short* Bs = smem + 4096;
  const int bx = by % 5, yy = by / 5;
  const unsigned short* B = yy < 12 ? Bk : Bv;
  const int m0 = bx * 128, n0 = (yy % 12) * 128;
  const bool act = tid < 256;
  const int t = tid;
  const int w = t >> 6, l = t & 63, lr = l & 15, lg = l >> 4;
  const int wr = w >> 1, wc = w & 1;
  const int srow = t >> 2, scol = (t & 3) * 8;

  f32x4 acc[4][4] = {};
  unsigned short* AsW = As + w * 512;
  unsigned short* BsW = Bs + w * 512;
  long ar0 = m0 + srow;       if (ar0 > Mc) ar0 = Mc;
  long ar1 = m0 + srow + 64;  if (ar1 > Mc) ar1 = Mc;

  for (int k0 = 0; k0 < K; k0 += 32) {
    if (act) {
      __builtin_amdgcn_global_load_lds(GLB_PTR(A + ar0 * (long)K + k0 + scol), LDS_PTR(AsW),        16, 0, 0);
      __builtin_amdgcn_global_load_lds(GLB_PTR(A + ar1 * (long)K + k0 + scol), LDS_PTR(AsW + 2048), 16, 0, 0);
      __builtin_amdgcn_global_load_lds(GLB_PTR(B + (long)(n0 + srow) * K + k0 + scol),      LDS_PTR(BsW),        16, 0, 0);
      __builtin_amdgcn_global_load_lds(GLB_PTR(B + (long)(n0 + srow + 64) * K + k0 + scol), LDS_PTR(BsW + 2048), 16, 0, 0);
    }
    __syncthreads();
    if (act) {
      short8 af[4], bfv[4];
#pragma unroll
      for (int i = 0; i < 4; ++i) {
        af[i]  = *(const short8*)(As + (wr * 64 + i * 16 + lr) * 32 + lg * 8);
        bfv[i] = *(const short8*)(Bs + (wc * 64 + i * 16 + lr) * 32 + lg * 8);
      }
#pragma unroll
      for (int i = 0; i < 4; ++i)
#pragma unroll
        for (int j = 0; j < 4; ++j)
          acc[i][j] = __builtin_amdgcn_mfma_f32_16x16x32_bf16(af[i], bfv[j], acc[i][j], 0, 0, 0);
    }
    __syncthreads();
  }

  if (!act) return;
  if (yy < 12) {
#pragma unroll
    for (int i = 0; i < 4; ++i) {
      int rb = m0 + wr * 64 + i * 16 + lg * 4;
#pragma unroll
      for (int j = 0; j < 4; ++j) {
        int col = n0 + wc * 64 + j * 16 + lr;
#pragma unroll
        for (int r = 0; r < 4; ++r)
          Ck[(long)(rb + r) * N + col] = f2bf(acc[i][j][r]);
      }
    }
  } else {
#pragma unroll
    for (int i = 0; i < 4; ++i) {
      int rb = m0 + wr * 64 + i * 16 + lg * 4;
#pragma unroll
      for (int j = 0; j < 4; ++j) {
        int col = n0 + wc * 64 + j * 16 + lr;
        int hh = col >> 6, dd = col & 63;
#pragma unroll
        for (int r = 0; r < 4; ++r) {
          int m = rb + r;
          if (m < 616) {
            int c = (unsigned)m / 154u;
            int e = m - c * 154;
            Vt[((long)((c * 24 + hh) * 64 + dd)) * 160 + e] = f2bf(acc[i][j][r]);
          }
        }
      }
    }
  }
}

// ---------------- merged Q-projection + K/V-projection launch ----------------
// blocks 0..767: Q GEMM (exactly one 3-blocks/CU fill); blocks 768..887: K/V projection (tail).
__global__ __launch_bounds__(512, 4) void gemm_q_kv(
    const unsigned short* __restrict__ HSb, const unsigned short* __restrict__ Wqb,
    unsigned short* __restrict__ Qb,
    const unsigned short* __restrict__ EHSb, const unsigned short* __restrict__ Wkb,
    const unsigned short* __restrict__ Wvb,
    unsigned short* __restrict__ Ck, unsigned short* __restrict__ Vt) {
  __shared__ unsigned short smem[24576];   // 49152 B: big path 2x(256+128)x32; kv path 2x 128x32
  if (blockIdx.x < 768)
    gemm_big_body<0>(HSb, Wqb, Qb, nullptr, nullptr, nullptr, smem, blockIdx.x, threadIdx.x);
  else
    gemm_kv_body(EHSb, Wkb, Wvb, Ck, Vt, smem, blockIdx.x - 768, threadIdx.x);
}

// ---------------- O-projection GEMM (MODE 1: + bias + residual, fp32 out) ----------------
__global__ __launch_bounds__(512, 4) void gemm_o(
    const unsigned short* __restrict__ Ob, const unsigned short* __restrict__ Wob,
    float* __restrict__ Cf, const float* __restrict__ bias, const float* __restrict__ resid) {
  __shared__ unsigned short smem[24576];
  gemm_big_body<1>(Ob, Wob, nullptr, Cf, bias, resid, smem, blockIdx.x, threadIdx.x);
}

// ---------------- fused cross-component attention ----------------
// grid (64 s-blocks, 24 heads), 256 thr = 4 waves; wave owns 16 s-rows, all 4 components.
// K/V register double-buffered; softmax WITHOUT max-subtraction (|scores| << 88, fp32-exp safe;
// ratio mathematically identical). P masked to 0 for e>=154. P[w] is WAVE-PRIVATE -> no
// __syncthreads anywhere (DS ops are wave-ordered; lgkm drains only). Output: stage wave's
// 16x64 tile in now-free P[w], then 128B-contiguous short8 stores.
__global__ __launch_bounds__(256) void attn_kernel(
    const unsigned short* __restrict__ Qb,   // [4*4096, 1536]
    const unsigned short* __restrict__ Kb,   // [640, 1536]; rows c*154+e (rows>=616 junk, masked)
    const unsigned short* __restrict__ Vt,   // [4][24][64][160]; e>=154 junk, masked via P
    const float* __restrict__ temp,
    unsigned short* __restrict__ Ob) {       // [4*4096, 1536]
  __shared__ unsigned short P[4][4][16][160];  // [wave][c][s][e] bf16 weights (wave-private)
  const int h = blockIdx.y, sb = blockIdx.x;
  const int t = threadIdx.x, w = t >> 6, l = t & 63, lr = l & 15, lg = l >> 4;
  const int s0 = sb * 64 + w * 16;
  const float sc = 1.0f / (temp[0] + 1e-8f);

  short8 qf[4][2];
#pragma unroll
  for (int c = 0; c < 4; ++c)
#pragma unroll
    for (int kt = 0; kt < 2; ++kt)
      qf[c][kt] = *(const short8*)(Qb + (long)(c * 4096 + s0 + lr) * 1536 + h * 64 + kt * 32 + lg * 8);

  short8 kA[4][2], kB[4][2];
  auto loadK = [&](int et, short8 (&k)[4][2]) {
#pragma unroll
    for (int c = 0; c < 4; ++c)
#pragma unroll
      for (int kt = 0; kt < 2; ++kt)
        k[c][kt] = *(const short8*)(Kb + (long)(c * 154 + et * 16 + lr) * 1536 + h * 64 + kt * 32 + lg * 8);
  };

  auto qk_step = [&](int et, short8 (&kc)[4][2], short8 (&kn)[4][2], bool pre) {
    if (pre) loadK(et + 1, kn);               // issue next-tile loads BEFORE dependent MFMAs
    f32x4 sa[4] = {};
#pragma unroll
    for (int c = 0; c < 4; ++c)
#pragma unroll
      for (int kt = 0; kt < 2; ++kt)
        sa[c] = __builtin_amdgcn_mfma_f32_16x16x32_bf16(kc[c][kt], qf[c][kt], sa[c], 0, 0, 0);
    float wv[4][4];
#pragma unroll
    for (int r = 0; r < 4; ++r) {
      float e0 = __expf(sa[0][r] * sc), e1 = __expf(sa[1][r] * sc);
      float e2 = __expf(sa[2][r] * sc), e3 = __expf(sa[3][r] * sc);
      float inv = 1.0f / (e0 + e1 + e2 + e3);
      wv[0][r] = e0 * inv; wv[1][r] = e1 * inv; wv[2][r] = e2 * inv; wv[3][r] = e3 * inv;
    }
#pragma unroll
    for (int c = 0; c < 4; ++c) {
      us4 pk;
#pragma unroll
      for (int r = 0; r < 4; ++r)
        pk[r] = (et * 16 + lg * 4 + r < 154) ? f2bf(wv[c][r]) : (unsigned short)0;
      *(us4*)&P[w][c][lr][et * 16 + lg * 4] = pk;
    }
  };

  loadK(0, kA);
#pragma unroll
  for (int et = 0; et < 10; et += 2) {
    qk_step(et,     kA, kB, true);
    qk_step(et + 1, kB, kA, et + 1 < 9);
  }
  asm volatile("s_waitcnt lgkmcnt(0)" ::: "memory");   // P writes drained (wave-private, no bar)
  __builtin_amdgcn_sched_barrier(0);

  // ---- PV with V-fragment register double-buffer ----
  short8 vA[4], vB[4];
  auto loadV = [&](int c, int ks, short8 (&v)[4]) {
#pragma unroll
    for (int nt = 0; nt < 4; ++nt)
      v[nt] = *(const short8*)(Vt + (long)((c * 24 + h) * 64 + nt * 16 + lr) * 160 + ks * 32 + lg * 8);
  };

  f32x4 o[4][4] = {};
  loadV(0, 0, vA);
#pragma unroll
  for (int p = 0; p < 10; ++p) {
    const int i0 = 2 * p, i1 = 2 * p + 1;
    const int c0 = i0 / 5, k0 = i0 % 5;
    const int c1 = i1 / 5, k1 = i1 % 5;
    loadV(c1, k1, vB);                        // prefetch odd step's V
    short8 pf0 = *(const short8*)&P[w][c0][lr][k0 * 32 + lg * 8];
#pragma unroll
    for (int nt = 0; nt < 4; ++nt)
      o[c0][nt] = __builtin_amdgcn_mfma_f32_16x16x32_bf16(pf0, vA[nt], o[c0][nt], 0, 0, 0);
    if (p < 9) loadV((i1 + 1) / 5, (i1 + 1) % 5, vA);   // prefetch next even step's V
    short8 pf1 = *(const short8*)&P[w][c1][lr][k1 * 32 + lg * 8];
#pragma unroll
    for (int nt = 0; nt < 4; ++nt)
      o[c1][nt] = __builtin_amdgcn_mfma_f32_16x16x32_bf16(pf1, vB[nt], o[c1][nt], 0, 0, 0);
  }

  // ---- coalesced Ob write: stage 16x64 tile in now-free wave-private P[w], 128B chunks ----
  unsigned short* OS = &P[w][0][0][0];        // PV's P reads all retired (consumed by MFMAs)
#pragma unroll
  for (int c = 0; c < 4; ++c) {
#pragma unroll
    for (int nt = 0; nt < 4; ++nt)
#pragma unroll
      for (int r = 0; r < 4; ++r)
        OS[(lg * 4 + r) * 64 + nt * 16 + lr] = f2bf(o[c][nt][r]);
    asm volatile("s_waitcnt lgkmcnt(0)" ::: "memory");  // scalar ds_writes drained
    __builtin_amdgcn_sched_barrier(0);
#pragma unroll
    for (int p = 0; p < 2; ++p) {
      const int flat = p * 512 + l * 8;       // elem index within 16x64 tile
      const int row = flat >> 6, col = flat & 63;
      short8 v = *(const short8*)(OS + flat);
      *(short8*)(Ob + (long)(c * 4096 + s0 + row) * 1536 + h * 64 + col) = v;
    }
  }
}

extern "C" void kernel_launch(void* const* d_in, const int* in_sizes, int n_in,
                              void* d_out, int out_size, void* d_ws, size_t ws_size,
                              hipStream_t stream) {
  (void)in_sizes; (void)n_in; (void)out_size; (void)ws_size;
  const float* HS  = (const float*)d_in[0];
  const float* EHS = (const float*)d_in[1];
  const float* TMP = (const float*)d_in[2];
  const float* Wq  = (const float*)d_in[3];
  const float* Wk  = (const float*)d_in[4];
  const float* Wv  = (const float*)d_in[5];
  const float* Wo  = (const float*)d_in[6];
  const float* bo  = (const float*)d_in[7];

  char* ws = (char*)d_ws;
  size_t off = 0;
  unsigned short* HSb  = (unsigned short*)(ws + off); off += (size_t)16384 * 1536 * 2;  // reused as Ob
  unsigned short* Ob   = HSb;
  unsigned short* EHSb = (unsigned short*)(ws + off); off += (size_t)616 * 1536 * 2;
  unsigned short* Wqb  = (unsigned short*)(ws + off); off += (size_t)1536 * 1536 * 2;
  unsigned short* Wkb  = (unsigned short*)(ws + off); off += (size_t)1536 * 1536 * 2;
  unsigned short* Wvb  = (unsigned short*)(ws + off); off += (size_t)1536 * 1536 * 2;
  unsigned short* Wob  = (unsigned short*)(ws + off); off += (size_t)1536 * 1536 * 2;
  unsigned short* Kb   = (unsigned short*)(ws + off); off += (size_t)640 * 1536 * 2;
  unsigned short* Vt   = (unsigned short*)(ws + off); off += (size_t)4 * 24 * 64 * 160 * 2;
  unsigned short* Qb   = (unsigned short*)d_out;  // bf16 scratch; final GEMM overwrites d_out fully

  cvt_all<<<2048, 256, 0, stream>>>(HS, EHS, Wq, Wk, Wv, Wo,
                                    HSb, EHSb, Wqb, Wkb, Wvb, Wob);

  gemm_q_kv<<<888, 512, 0, stream>>>(HSb, Wqb, Qb, EHSb, Wkb, Wvb, Kb, Vt);

  attn_kernel<<<dim3(64, 24), 256, 0, stream>>>(Qb, Kb, Vt, TMP, Ob);

  gemm_o<<<768, 512, 0, stream>>>(Ob, Wob, (float*)d_out, bo, HS);
}

// Round 17
// 343.897 us; speedup vs baseline: 1.1241x; 1.0292x over previous
//
#include <hip/hip_runtime.h>

typedef __attribute__((ext_vector_type(8))) short short8;
typedef __attribute__((ext_vector_type(4))) float f32x4;
typedef __attribute__((ext_vector_type(4))) unsigned short us4;
typedef __attribute__((ext_vector_type(4))) float float4v;

#define GLB_PTR(p) ((const __attribute__((address_space(1))) void*)(p))
#define LDS_PTR(p) ((__attribute__((address_space(3))) void*)(p))

__device__ __forceinline__ unsigned short f2bf(float f) {
  unsigned int u = __float_as_uint(f);
  u += 0x7FFF + ((u >> 16) & 1);   // round-to-nearest-even
  return (unsigned short)(u >> 16);
}

// ---------------- all fp32 -> bf16 converts, ONE flattened grid-stride range ----------------
__global__ void cvt_all(const float* __restrict__ i0, const float* __restrict__ i1,
                        const float* __restrict__ i2, const float* __restrict__ i3,
                        const float* __restrict__ i4, const float* __restrict__ i5,
                        unsigned short* __restrict__ o0, unsigned short* __restrict__ o1,
                        unsigned short* __restrict__ o2, unsigned short* __restrict__ o3,
                        unsigned short* __restrict__ o4, unsigned short* __restrict__ o5) {
  constexpr int N0 = 16384 * 1536 / 4, N1 = 616 * 1536 / 4, NW = 1536 * 1536 / 4;
  constexpr int TOT = N0 + N1 + 4 * NW;   // 8,887,296 x 4-elem groups
  int i = blockIdx.x * blockDim.x + threadIdx.x;
  const int stride = gridDim.x * blockDim.x;
  for (; i < TOT; i += stride) {
    const float* in; unsigned short* out; int j = i;
    if (j < N0)              { in = i0; out = o0; }
    else if ((j -= N0) < N1) { in = i1; out = o1; }
    else {
      j -= N1;
      const int t = j / NW; j -= t * NW;
      in  = t == 0 ? i2 : t == 1 ? i3 : t == 2 ? i4 : i5;
      out = t == 0 ? o2 : t == 1 ? o3 : t == 2 ? o4 : o5;
    }
    float4v v = *(const float4v*)(in + (size_t)j * 4);
    us4 o;
    o[0] = f2bf(v[0]); o[1] = f2bf(v[1]); o[2] = f2bf(v[2]); o[3] = f2bf(v[3]);
    *(us4*)(out + (size_t)j * 4) = o;
  }
}

// ---------------- big bf16 GEMM body: C[16384,1536] = A[16384,1536] * B[1536,1536]^T ------------
// r14 measured-best structure (655 TF, 118.5 us) + r4's MEASURED-0-CONFLICT swizzle:
// LDS[row][g] holds global granule g ^ ((row>>1)&3) (both sides, involution) -> 2 lanes/bank
// on ds_read_b128 (free, m136) vs old 4-way (9.4M conflict-cy/dispatch).
// 256x128 block tile, BK=32, 8 waves (4M x 2N), wave tile 64x64 (acc[4][4]=64 VGPR, no spill).
// DEPTH-2 LDS (48 KB -> 3 blocks/CU; grid 768 = EXACTLY one fill; 6 waves/SIMD).
// Per iter: vmcnt(3) -> barrier -> frag-reads -> lgkm(0) -> barrier -> stage(kt+2) -> MFMA.
// MODE 0: C bf16.  MODE 1: C fp32 = acc + bias[n] + resid[m,n].
template<int MODE>
__device__ __forceinline__ void gemm_big_body(
    const unsigned short* __restrict__ A,
    const unsigned short* __restrict__ B,
    unsigned short* __restrict__ Cb,
    float* __restrict__ Cf,
    const float* __restrict__ bias,
    const float* __restrict__ resid,
    unsigned short* smem, int bid, int tid) {
  constexpr int K = 1536, N = 1536, BK = 32, NKT = K / BK;  // 48 K-tiles
  unsigned short* As = smem;             // 2 x 256x32 elems
  unsigned short* Bs = smem + 2 * 8192;  // 2 x 128x32 elems

  // XCD-chunked swizzle: 768 blocks -> 96/XCD = 8 m-tiles x 12 n-tiles, n fastest
  const int xcd = bid & 7, idx = bid >> 3;
  const int m0 = (xcd * 8 + idx / 12) * 256;
  const int n0 = (idx % 12) * 128;

  const int w = tid >> 6, l = tid & 63, lr = l & 15, lg = l >> 4;
  const int wr = w >> 1, wc = w & 1;               // 4M x 2N wave grid
  const int ga = lg ^ ((lr >> 1) & 3);             // 0-conflict read granule (r4-verified)

  const int srow = w * 16 + (l >> 2);              // staging row 0..127
  const int sg = (l & 3) ^ ((l >> 3) & 3);         // source granule: g ^ ((row>>1)&3), involution
  const unsigned short* aSrc = A + (size_t)(m0 + srow) * K + sg * 8;
  const unsigned short* bSrc = B + (size_t)(n0 + srow) * K + sg * 8;

  f32x4 acc[4][4] = {};

  auto stage = [&](int buf, int kt) {              // 3 loads/wave
    const int k0 = kt * BK;
    unsigned short* AsW = As + buf * 8192 + w * 512;   // wave-uniform base
    unsigned short* BsW = Bs + buf * 4096 + w * 512;
    __builtin_amdgcn_global_load_lds(GLB_PTR(aSrc + k0),                    LDS_PTR(AsW),        16, 0, 0);
    __builtin_amdgcn_global_load_lds(GLB_PTR(aSrc + (size_t)128 * K + k0),  LDS_PTR(AsW + 4096), 16, 0, 0);
    __builtin_amdgcn_global_load_lds(GLB_PTR(bSrc + k0),                    LDS_PTR(BsW),        16, 0, 0);
  };

  auto loadfrags = [&](int buf, short8* af, short8* bfv) {
    const unsigned short* Asb = As + buf * 8192;
    const unsigned short* Bsb = Bs + buf * 4096;
#pragma unroll
    for (int i = 0; i < 4; ++i)
      af[i] = *(const short8*)(Asb + (wr * 64 + i * 16 + lr) * 32 + ga * 8);
#pragma unroll
    for (int j = 0; j < 4; ++j)
      bfv[j] = *(const short8*)(Bsb + (wc * 64 + j * 16 + lr) * 32 + ga * 8);
  };

  auto mfma_all = [&](short8* af, short8* bfv) {
#pragma unroll
    for (int i = 0; i < 4; ++i)
#pragma unroll
      for (int j = 0; j < 4; ++j)
        acc[i][j] = __builtin_amdgcn_mfma_f32_16x16x32_bf16(af[i], bfv[j], acc[i][j], 0, 0, 0);
  };

  // prologue: 2 K-tiles in flight (6 loads/wave)
  stage(0, 0); stage(1, 1);

  for (int kt = 0; kt < NKT; ++kt) {
    if (kt < NKT - 1) asm volatile("s_waitcnt vmcnt(3)" ::: "memory");  // stage(kt) retired
    else              asm volatile("s_waitcnt vmcnt(0)" ::: "memory");
    __builtin_amdgcn_s_barrier();                       // join: buf kt&1 valid everywhere
    __builtin_amdgcn_sched_barrier(0);
    short8 af[4], bfv[4];
    loadfrags(kt & 1, af, bfv);
    asm volatile("s_waitcnt lgkmcnt(0)" ::: "memory");  // frags in regs
    __builtin_amdgcn_sched_barrier(0);
    __builtin_amdgcn_s_barrier();                       // all waves done reading buf kt&1
    __builtin_amdgcn_sched_barrier(0);
    if (kt + 2 < NKT) stage(kt & 1, kt + 2);            // overwrite freed buffer
    __builtin_amdgcn_s_setprio(1);
    mfma_all(af, bfv);
    __builtin_amdgcn_s_setprio(0);
  }

#pragma unroll
  for (int i = 0; i < 4; ++i) {
    const int rb = m0 + wr * 64 + i * 16 + lg * 4;
#pragma unroll
    for (int j = 0; j < 4; ++j) {
      const int col = n0 + wc * 64 + j * 16 + lr;
#pragma unroll
      for (int r = 0; r < 4; ++r) {
        size_t o = (size_t)(rb + r) * N + col;
        if (MODE == 0) Cb[o] = f2bf(acc[i][j][r]);
        else           Cf[o] = acc[i][j][r] + bias[col] + resid[o];
      }
    }
  }
}

// ---------------- K+V projection body (runs in waves 0-3; waves 4-7 barrier-only) ----------------
// yy<12: Ck row-major bf16.  yy>=12: Vt[c][h][d][e(160)] transposed write (e>=154 junk, masked in attn).
__device__ __forceinline__ void gemm_kv_body(
    const unsigned short* __restrict__ A,    // EHSb [616,1536]
    const unsigned short* __restrict__ Bk,
    const unsigned short* __restrict__ Bv,
    unsigned short* __restrict__ Ck,
    unsigned short* __restrict__ Vt,
    unsigned short* smem, int by, int tid) {
  constexpr int K = 1536, N = 1536, Mc = 615;
  unsigned short* As = smem;
  unsigned short* Bs = smem + 4096;
  const int bx = by % 5, yy = by / 5;
  const unsigned short* B = yy < 12 ? Bk : Bv;
  const int m0 = bx * 128, n0 = (yy % 12) * 128;
  const bool act = tid < 256;
  const int t = tid;
  const int w = t >> 6, l = t & 63, lr = l & 15, lg = l >> 4;
  const int wr = w >> 1, wc = w & 1;
  const int srow = t >> 2, scol = (t & 3) * 8;

  f32x4 acc[4][4] = {};
  unsigned short* AsW = As + w * 512;
  unsigned short* BsW = Bs + w * 512;
  long ar0 = m0 + srow;       if (ar0 > Mc) ar0 = Mc;
  long ar1 = m0 + srow + 64;  if (ar1 > Mc) ar1 = Mc;

  for (int k0 = 0; k0 < K; k0 += 32) {
    if (act) {
      __builtin_amdgcn_global_load_lds(GLB_PTR(A + ar0 * (long)K + k0 + scol), LDS_PTR(AsW),        16, 0, 0);
      __builtin_amdgcn_global_load_lds(GLB_PTR(A + ar1 * (long)K + k0 + scol), LDS_PTR(AsW + 2048), 16, 0, 0);
      __builtin_amdgcn_global_load_lds(GLB_PTR(B + (long)(n0 + srow) * K + k0 + scol),      LDS_PTR(BsW),        16, 0, 0);
      __builtin_amdgcn_global_load_lds(GLB_PTR(B + (long)(n0 + srow + 64) * K + k0 + scol), LDS_PTR(BsW + 2048), 16, 0, 0);
    }
    __syncthreads();
    if (act) {
      short8 af[4], bfv[4];
#pragma unroll
      for (int i = 0; i < 4; ++i) {
        af[i]  = *(const short8*)(As + (wr * 64 + i * 16 + lr) * 32 + lg * 8);
        bfv[i] = *(const short8*)(Bs + (wc * 64 + i * 16 + lr) * 32 + lg * 8);
      }
#pragma unroll
      for (int i = 0; i < 4; ++i)
#pragma unroll
        for (int j = 0; j < 4; ++j)
          acc[i][j] = __builtin_amdgcn_mfma_f32_16x16x32_bf16(af[i], bfv[j], acc[i][j], 0, 0, 0);
    }
    __syncthreads();
  }

  if (!act) return;
  if (yy < 12) {
#pragma unroll
    for (int i = 0; i < 4; ++i) {
      int rb = m0 + wr * 64 + i * 16 + lg * 4;
#pragma unroll
      for (int j = 0; j < 4; ++j) {
        int col = n0 + wc * 64 + j * 16 + lr;
#pragma unroll
        for (int r = 0; r < 4; ++r)
          Ck[(long)(rb + r) * N + col] = f2bf(acc[i][j][r]);
      }
    }
  } else {
#pragma unroll
    for (int i = 0; i < 4; ++i) {
      int rb = m0 + wr * 64 + i * 16 + lg * 4;
#pragma unroll
      for (int j = 0; j < 4; ++j) {
        int col = n0 + wc * 64 + j * 16 + lr;
        int hh = col >> 6, dd = col & 63;
#pragma unroll
        for (int r = 0; r < 4; ++r) {
          int m = rb + r;
          if (m < 616) {
            int c = (unsigned)m / 154u;
            int e = m - c * 154;
            Vt[((long)((c * 24 + hh) * 64 + dd)) * 160 + e] = f2bf(acc[i][j][r]);
          }
        }
      }
    }
  }
}

// ---------------- merged Q-projection + K/V-projection launch ----------------
// blocks 0..767: Q GEMM (exactly one 3-blocks/CU fill); blocks 768..887: K/V projection (tail).
__global__ __launch_bounds__(512, 4) void gemm_q_kv(
    const unsigned short* __restrict__ HSb, const unsigned short* __restrict__ Wqb,
    unsigned short* __restrict__ Qb,
    const unsigned short* __restrict__ EHSb, const unsigned short* __restrict__ Wkb,
    const unsigned short* __restrict__ Wvb,
    unsigned short* __restrict__ Ck, unsigned short* __restrict__ Vt) {
  __shared__ unsigned short smem[24576];   // 49152 B: big path 2x(256+128)x32; kv path 2x 128x32
  if (blockIdx.x < 768)
    gemm_big_body<0>(HSb, Wqb, Qb, nullptr, nullptr, nullptr, smem, blockIdx.x, threadIdx.x);
  else
    gemm_kv_body(EHSb, Wkb, Wvb, Ck, Vt, smem, blockIdx.x - 768, threadIdx.x);
}

// ---------------- O-projection GEMM (MODE 1: + bias + residual, fp32 out) ----------------
__global__ __launch_bounds__(512, 4) void gemm_o(
    const unsigned short* __restrict__ Ob, const unsigned short* __restrict__ Wob,
    float* __restrict__ Cf, const float* __restrict__ bias, const float* __restrict__ resid) {
  __shared__ unsigned short smem[24576];
  gemm_big_body<1>(Ob, Wob, nullptr, Cf, bias, resid, smem, blockIdx.x, threadIdx.x);
}

// ---------------- fused cross-component attention ----------------
// grid (64 s-blocks, 24 heads), 256 thr = 4 waves; wave owns 16 s-rows, all 4 components.
// K/V register double-buffered; softmax WITHOUT max-subtraction (|scores| << 88, fp32-exp safe;
// ratio mathematically identical). P masked to 0 for e>=154. P[w] is WAVE-PRIVATE -> no
// __syncthreads anywhere (DS ops are wave-ordered; lgkm drains only). Output: stage wave's
// 16x64 tile in now-free P[w], then 128B-contiguous short8 stores.
__global__ __launch_bounds__(256) void attn_kernel(
    const unsigned short* __restrict__ Qb,   // [4*4096, 1536]
    const unsigned short* __restrict__ Kb,   // [640, 1536]; rows c*154+e (rows>=616 junk, masked)
    const unsigned short* __restrict__ Vt,   // [4][24][64][160]; e>=154 junk, masked via P
    const float* __restrict__ temp,
    unsigned short* __restrict__ Ob) {       // [4*4096, 1536]
  __shared__ unsigned short P[4][4][16][160];  // [wave][c][s][e] bf16 weights (wave-private)
  const int h = blockIdx.y, sb = blockIdx.x;
  const int t = threadIdx.x, w = t >> 6, l = t & 63, lr = l & 15, lg = l >> 4;
  const int s0 = sb * 64 + w * 16;
  const float sc = 1.0f / (temp[0] + 1e-8f);

  short8 qf[4][2];
#pragma unroll
  for (int c = 0; c < 4; ++c)
#pragma unroll
    for (int kt = 0; kt < 2; ++kt)
      qf[c][kt] = *(const short8*)(Qb + (long)(c * 4096 + s0 + lr) * 1536 + h * 64 + kt * 32 + lg * 8);

  short8 kA[4][2], kB[4][2];
  auto loadK = [&](int et, short8 (&k)[4][2]) {
#pragma unroll
    for (int c = 0; c < 4; ++c)
#pragma unroll
      for (int kt = 0; kt < 2; ++kt)
        k[c][kt] = *(const short8*)(Kb + (long)(c * 154 + et * 16 + lr) * 1536 + h * 64 + kt * 32 + lg * 8);
  };

  auto qk_step = [&](int et, short8 (&kc)[4][2], short8 (&kn)[4][2], bool pre) {
    if (pre) loadK(et + 1, kn);               // issue next-tile loads BEFORE dependent MFMAs
    f32x4 sa[4] = {};
#pragma unroll
    for (int c = 0; c < 4; ++c)
#pragma unroll
      for (int kt = 0; kt < 2; ++kt)
        sa[c] = __builtin_amdgcn_mfma_f32_16x16x32_bf16(kc[c][kt], qf[c][kt], sa[c], 0, 0, 0);
    float wv[4][4];
#pragma unroll
    for (int r = 0; r < 4; ++r) {
      float e0 = __expf(sa[0][r] * sc), e1 = __expf(sa[1][r] * sc);
      float e2 = __expf(sa[2][r] * sc), e3 = __expf(sa[3][r] * sc);
      float inv = 1.0f / (e0 + e1 + e2 + e3);
      wv[0][r] = e0 * inv; wv[1][r] = e1 * inv; wv[2][r] = e2 * inv; wv[3][r] = e3 * inv;
    }
#pragma unroll
    for (int c = 0; c < 4; ++c) {
      us4 pk;
#pragma unroll
      for (int r = 0; r < 4; ++r)
        pk[r] = (et * 16 + lg * 4 + r < 154) ? f2bf(wv[c][r]) : (unsigned short)0;
      *(us4*)&P[w][c][lr][et * 16 + lg * 4] = pk;
    }
  };

  loadK(0, kA);
#pragma unroll
  for (int et = 0; et < 10; et += 2) {
    qk_step(et,     kA, kB, true);
    qk_step(et + 1, kB, kA, et + 1 < 9);
  }
  asm volatile("s_waitcnt lgkmcnt(0)" ::: "memory");   // P writes drained (wave-private, no bar)
  __builtin_amdgcn_sched_barrier(0);

  // ---- PV with V-fragment register double-buffer ----
  short8 vA[4], vB[4];
  auto loadV = [&](int c, int ks, short8 (&v)[4]) {
#pragma unroll
    for (int nt = 0; nt < 4; ++nt)
      v[nt] = *(const short8*)(Vt + (long)((c * 24 + h) * 64 + nt * 16 + lr) * 160 + ks * 32 + lg * 8);
  };

  f32x4 o[4][4] = {};
  loadV(0, 0, vA);
#pragma unroll
  for (int p = 0; p < 10; ++p) {
    const int i0 = 2 * p, i1 = 2 * p + 1;
    const int c0 = i0 / 5, k0 = i0 % 5;
    const int c1 = i1 / 5, k1 = i1 % 5;
    loadV(c1, k1, vB);                        // prefetch odd step's V
    short8 pf0 = *(const short8*)&P[w][c0][lr][k0 * 32 + lg * 8];
#pragma unroll
    for (int nt = 0; nt < 4; ++nt)
      o[c0][nt] = __builtin_amdgcn_mfma_f32_16x16x32_bf16(pf0, vA[nt], o[c0][nt], 0, 0, 0);
    if (p < 9) loadV((i1 + 1) / 5, (i1 + 1) % 5, vA);   // prefetch next even step's V
    short8 pf1 = *(const short8*)&P[w][c1][lr][k1 * 32 + lg * 8];
#pragma unroll
    for (int nt = 0; nt < 4; ++nt)
      o[c1][nt] = __builtin_amdgcn_mfma_f32_16x16x32_bf16(pf1, vB[nt], o[c1][nt], 0, 0, 0);
  }

  // ---- coalesced Ob write: stage 16x64 tile in now-free wave-private P[w], 128B chunks ----
  unsigned short* OS = &P[w][0][0][0];        // PV's P reads all retired (consumed by MFMAs)
#pragma unroll
  for (int c = 0; c < 4; ++c) {
#pragma unroll
    for (int nt = 0; nt < 4; ++nt)
#pragma unroll
      for (int r = 0; r < 4; ++r)
        OS[(lg * 4 + r) * 64 + nt * 16 + lr] = f2bf(o[c][nt][r]);
    asm volatile("s_waitcnt lgkmcnt(0)" ::: "memory");  // scalar ds_writes drained
    __builtin_amdgcn_sched_barrier(0);
#pragma unroll
    for (int p = 0; p < 2; ++p) {
      const int flat = p * 512 + l * 8;       // elem index within 16x64 tile
      const int row = flat >> 6, col = flat & 63;
      short8 v = *(const short8*)(OS + flat);
      *(short8*)(Ob + (long)(c * 4096 + s0 + row) * 1536 + h * 64 + col) = v;
    }
  }
}

extern "C" void kernel_launch(void* const* d_in, const int* in_sizes, int n_in,
                              void* d_out, int out_size, void* d_ws, size_t ws_size,
                              hipStream_t stream) {
  (void)in_sizes; (void)n_in; (void)out_size; (void)ws_size;
  const float* HS  = (const float*)d_in[0];
  const float* EHS = (const float*)d_in[1];
  const float* TMP = (const float*)d_in[2];
  const float* Wq  = (const float*)d_in[3];
  const float* Wk  = (const float*)d_in[4];
  const float* Wv  = (const float*)d_in[5];
  const float* Wo  = (const float*)d_in[6];
  const float* bo  = (const float*)d_in[7];

  char* ws = (char*)d_ws;
  size_t off = 0;
  unsigned short* HSb  = (unsigned short*)(ws + off); off += (size_t)16384 * 1536 * 2;  // reused as Ob
  unsigned short* Ob   = HSb;
  unsigned short* EHSb = (unsigned short*)(ws + off); off += (size_t)616 * 1536 * 2;
  unsigned short* Wqb  = (unsigned short*)(ws + off); off += (size_t)1536 * 1536 * 2;
  unsigned short* Wkb  = (unsigned short*)(ws + off); off += (size_t)1536 * 1536 * 2;
  unsigned short* Wvb  = (unsigned short*)(ws + off); off += (size_t)1536 * 1536 * 2;
  unsigned short* Wob  = (unsigned short*)(ws + off); off += (size_t)1536 * 1536 * 2;
  unsigned short* Kb   = (unsigned short*)(ws + off); off += (size_t)640 * 1536 * 2;
  unsigned short* Vt   = (unsigned short*)(ws + off); off += (size_t)4 * 24 * 64 * 160 * 2;
  unsigned short* Qb   = (unsigned short*)d_out;  // bf16 scratch; final GEMM overwrites d_out fully

  cvt_all<<<2048, 256, 0, stream>>>(HS, EHS, Wq, Wk, Wv, Wo,
                                    HSb, EHSb, Wqb, Wkb, Wvb, Wob);

  gemm_q_kv<<<888, 512, 0, stream>>>(HSb, Wqb, Qb, EHSb, Wkb, Wvb, Kb, Vt);

  attn_kernel<<<dim3(64, 24), 256, 0, stream>>>(Qb, Kb, Vt, TMP, Ob);

  gemm_o<<<768, 512, 0, stream>>>(Ob, Wob, (float*)d_out, bo, HS);
}

// Round 18
// 337.916 us; speedup vs baseline: 1.1440x; 1.0177x over previous
//
#include <hip/hip_runtime.h>

typedef __attribute__((ext_vector_type(8))) short short8;
typedef __attribute__((ext_vector_type(4))) float f32x4;
typedef __attribute__((ext_vector_type(4))) unsigned short us4;
typedef __attribute__((ext_vector_type(4))) float float4v;

#define GLB_PTR(p) ((const __attribute__((address_space(1))) void*)(p))
#define LDS_PTR(p) ((__attribute__((address_space(3))) void*)(p))

__device__ __forceinline__ unsigned short f2bf(float f) {
  unsigned int u = __float_as_uint(f);
  u += 0x7FFF + ((u >> 16) & 1);   // round-to-nearest-even
  return (unsigned short)(u >> 16);
}

// ---------------- all fp32 -> bf16 converts, ONE flattened grid-stride range ----------------
__global__ void cvt_all(const float* __restrict__ i0, const float* __restrict__ i1,
                        const float* __restrict__ i2, const float* __restrict__ i3,
                        const float* __restrict__ i4, const float* __restrict__ i5,
                        unsigned short* __restrict__ o0, unsigned short* __restrict__ o1,
                        unsigned short* __restrict__ o2, unsigned short* __restrict__ o3,
                        unsigned short* __restrict__ o4, unsigned short* __restrict__ o5) {
  constexpr int N0 = 16384 * 1536 / 4, N1 = 616 * 1536 / 4, NW = 1536 * 1536 / 4;
  constexpr int TOT = N0 + N1 + 4 * NW;   // 8,887,296 x 4-elem groups
  int i = blockIdx.x * blockDim.x + threadIdx.x;
  const int stride = gridDim.x * blockDim.x;
  for (; i < TOT; i += stride) {
    const float* in; unsigned short* out; int j = i;
    if (j < N0)              { in = i0; out = o0; }
    else if ((j -= N0) < N1) { in = i1; out = o1; }
    else {
      j -= N1;
      const int t = j / NW; j -= t * NW;
      in  = t == 0 ? i2 : t == 1 ? i3 : t == 2 ? i4 : i5;
      out = t == 0 ? o2 : t == 1 ? o3 : t == 2 ? o4 : o5;
    }
    float4v v = *(const float4v*)(in + (size_t)j * 4);
    us4 o;
    o[0] = f2bf(v[0]); o[1] = f2bf(v[1]); o[2] = f2bf(v[2]); o[3] = f2bf(v[3]);
    *(us4*)(out + (size_t)j * 4) = o;
  }
}

// ---------------- big bf16 GEMM body: C[16384,1536] = A[16384,1536] * B[1536,1536]^T ------------
// r17 diagnosis: 8-wave 64x64 wave tile was LDS-read-bound (2260 cy > MFMA 1860 cy per CU-iter).
// This round: 4 waves (2M x 2N), wave tile 128x64 (acc[8][4]) -> LDS 48 KB/block-iter
// (1690 cy < MFMA 1860 cy), keeping r14's DEPTH-2 48 KB LDS (3 blocks/CU; grid 768 = exact
// fill) and r17's 0-CONFLICT swizzle: LDS[row][g] holds global granule g^((row>>1)&3).
// Per iter: vmcnt(6) -> barrier -> frag-reads(12) -> lgkm(0) -> barrier -> stage(kt+2) -> MFMA.
// __launch_bounds__(256,2): r9-proven no-spill for acc[8][4] (VGPR 124 + 128 AGPR).
// MODE 0: C bf16.  MODE 1: C fp32 = acc + bias[n] + resid[m,n].
template<int MODE>
__device__ __forceinline__ void gemm_big_body(
    const unsigned short* __restrict__ A,
    const unsigned short* __restrict__ B,
    unsigned short* __restrict__ Cb,
    float* __restrict__ Cf,
    const float* __restrict__ bias,
    const float* __restrict__ resid,
    unsigned short* smem, int bid, int tid) {
  constexpr int K = 1536, N = 1536, BK = 32, NKT = K / BK;  // 48 K-tiles
  unsigned short* As = smem;             // 2 x 256x32 elems
  unsigned short* Bs = smem + 2 * 8192;  // 2 x 128x32 elems

  // XCD-chunked swizzle: 768 blocks -> 96/XCD = 8 m-tiles x 12 n-tiles, n fastest
  const int xcd = bid & 7, idx = bid >> 3;
  const int m0 = (xcd * 8 + idx / 12) * 256;
  const int n0 = (idx % 12) * 128;

  const int w = tid >> 6, l = tid & 63, lr = l & 15, lg = l >> 4;
  const int wr = w >> 1, wc = w & 1;               // 2M x 2N wave grid, wave tile 128x64
  const int ga = lg ^ ((lr >> 1) & 3);             // 0-conflict read granule (r17-verified)

  const int srow = tid >> 2;                       // staging row 0..63 (+i*64 chunks)
  const int sg = (l & 3) ^ ((l >> 3) & 3);         // source granule: g ^ ((row>>1)&3), involution
  const unsigned short* aSrc = A + (size_t)(m0 + srow) * K + sg * 8;
  const unsigned short* bSrc = B + (size_t)(n0 + srow) * K + sg * 8;

  f32x4 acc[8][4] = {};

  auto stage = [&](int buf, int kt) {              // 6 loads/wave
    const int k0 = kt * BK;
    unsigned short* AsW = As + buf * 8192 + w * 512;   // wave-uniform base
    unsigned short* BsW = Bs + buf * 4096 + w * 512;
#pragma unroll
    for (int i = 0; i < 4; ++i)
      __builtin_amdgcn_global_load_lds(GLB_PTR(aSrc + (size_t)(i * 64) * K + k0), LDS_PTR(AsW + i * 2048), 16, 0, 0);
#pragma unroll
    for (int i = 0; i < 2; ++i)
      __builtin_amdgcn_global_load_lds(GLB_PTR(bSrc + (size_t)(i * 64) * K + k0), LDS_PTR(BsW + i * 2048), 16, 0, 0);
  };

  auto loadfrags = [&](int buf, short8* af, short8* bfv) {
    const unsigned short* Asb = As + buf * 8192;
    const unsigned short* Bsb = Bs + buf * 4096;
#pragma unroll
    for (int i = 0; i < 8; ++i)
      af[i] = *(const short8*)(Asb + (wr * 128 + i * 16 + lr) * 32 + ga * 8);
#pragma unroll
    for (int j = 0; j < 4; ++j)
      bfv[j] = *(const short8*)(Bsb + (wc * 64 + j * 16 + lr) * 32 + ga * 8);
  };

  auto mfma_all = [&](short8* af, short8* bfv) {
#pragma unroll
    for (int i = 0; i < 8; ++i)
#pragma unroll
      for (int j = 0; j < 4; ++j)
        acc[i][j] = __builtin_amdgcn_mfma_f32_16x16x32_bf16(af[i], bfv[j], acc[i][j], 0, 0, 0);
  };

  // prologue: 2 K-tiles in flight (12 loads/wave)
  stage(0, 0); stage(1, 1);

  for (int kt = 0; kt < NKT; ++kt) {
    if (kt < NKT - 1) asm volatile("s_waitcnt vmcnt(6)" ::: "memory");  // stage(kt) retired
    else              asm volatile("s_waitcnt vmcnt(0)" ::: "memory");
    __builtin_amdgcn_s_barrier();                       // join: buf kt&1 valid everywhere
    __builtin_amdgcn_sched_barrier(0);
    short8 af[8], bfv[4];
    loadfrags(kt & 1, af, bfv);
    asm volatile("s_waitcnt lgkmcnt(0)" ::: "memory");  // frags in regs
    __builtin_amdgcn_sched_barrier(0);
    __builtin_amdgcn_s_barrier();                       // all waves done reading buf kt&1
    __builtin_amdgcn_sched_barrier(0);
    if (kt + 2 < NKT) stage(kt & 1, kt + 2);            // overwrite freed buffer
    __builtin_amdgcn_s_setprio(1);
    mfma_all(af, bfv);
    __builtin_amdgcn_s_setprio(0);
  }

#pragma unroll
  for (int i = 0; i < 8; ++i) {
    const int rb = m0 + wr * 128 + i * 16 + lg * 4;
#pragma unroll
    for (int j = 0; j < 4; ++j) {
      const int col = n0 + wc * 64 + j * 16 + lr;
#pragma unroll
      for (int r = 0; r < 4; ++r) {
        size_t o = (size_t)(rb + r) * N + col;
        if (MODE == 0) Cb[o] = f2bf(acc[i][j][r]);
        else           Cf[o] = acc[i][j][r] + bias[col] + resid[o];
      }
    }
  }
}

// ---------------- K+V projection body (256 threads) ----------------
// yy<12: Ck row-major bf16.  yy>=12: Vt[c][h][d][e(160)] transposed write (e>=154 junk, masked in attn).
__device__ __forceinline__ void gemm_kv_body(
    const unsigned short* __restrict__ A,    // EHSb [616,1536]
    const unsigned short* __restrict__ Bk,
    const unsigned short* __restrict__ Bv,
    unsigned short* __restrict__ Ck,
    unsigned short* __restrict__ Vt,
    unsigned short* smem, int by, int tid) {
  constexpr int K = 1536, N = 1536, Mc = 615;
  unsigned short* As = smem;
  unsigned short* Bs = smem + 4096;
  const int bx = by % 5, yy = by / 5;
  const unsigned short* B = yy < 12 ? Bk : Bv;
  const int m0 = bx * 128, n0 = (yy % 12) * 128;
  const int t = tid;
  const int w = t >> 6, l = t & 63, lr = l & 15, lg = l >> 4;
  const int wr = w >> 1, wc = w & 1;
  const int srow = t >> 2, scol = (t & 3) * 8;

  f32x4 acc[4][4] = {};
  unsigned short* AsW = As + w * 512;
  unsigned short* BsW = Bs + w * 512;
  long ar0 = m0 + srow;       if (ar0 > Mc) ar0 = Mc;
  long ar1 = m0 + srow + 64;  if (ar1 > Mc) ar1 = Mc;

  for (int k0 = 0; k0 < K; k0 += 32) {
    __builtin_amdgcn_global_load_lds(GLB_PTR(A + ar0 * (long)K + k0 + scol), LDS_PTR(AsW),        16, 0, 0);
    __builtin_amdgcn_global_load_lds(GLB_PTR(A + ar1 * (long)K + k0 + scol), LDS_PTR(AsW + 2048), 16, 0, 0);
    __builtin_amdgcn_global_load_lds(GLB_PTR(B + (long)(n0 + srow) * K + k0 + scol),      LDS_PTR(BsW),        16, 0, 0);
    __builtin_amdgcn_global_load_lds(GLB_PTR(B + (long)(n0 + srow + 64) * K + k0 + scol), LDS_PTR(BsW + 2048), 16, 0, 0);
    __syncthreads();

    short8 af[4], bfv[4];
#pragma unroll
    for (int i = 0; i < 4; ++i) {
      af[i]  = *(const short8*)(As + (wr * 64 + i * 16 + lr) * 32 + lg * 8);
      bfv[i] = *(const short8*)(Bs + (wc * 64 + i * 16 + lr) * 32 + lg * 8);
    }
#pragma unroll
    for (int i = 0; i < 4; ++i)
#pragma unroll
      for (int j = 0; j < 4; ++j)
        acc[i][j] = __builtin_amdgcn_mfma_f32_16x16x32_bf16(af[i], bfv[j], acc[i][j], 0, 0, 0);
    __syncthreads();
  }

  if (yy < 12) {
#pragma unroll
    for (int i = 0; i < 4; ++i) {
      int rb = m0 + wr * 64 + i * 16 + lg * 4;
#pragma unroll
      for (int j = 0; j < 4; ++j) {
        int col = n0 + wc * 64 + j * 16 + lr;
#pragma unroll
        for (int r = 0; r < 4; ++r)
          Ck[(long)(rb + r) * N + col] = f2bf(acc[i][j][r]);
      }
    }
  } else {
#pragma unroll
    for (int i = 0; i < 4; ++i) {
      int rb = m0 + wr * 64 + i * 16 + lg * 4;
#pragma unroll
      for (int j = 0; j < 4; ++j) {
        int col = n0 + wc * 64 + j * 16 + lr;
        int hh = col >> 6, dd = col & 63;
#pragma unroll
        for (int r = 0; r < 4; ++r) {
          int m = rb + r;
          if (m < 616) {
            int c = (unsigned)m / 154u;
            int e = m - c * 154;
            Vt[((long)((c * 24 + hh) * 64 + dd)) * 160 + e] = f2bf(acc[i][j][r]);
          }
        }
      }
    }
  }
}

// ---------------- merged Q-projection + K/V-projection launch ----------------
// blocks 0..767: Q GEMM (exactly one 3-blocks/CU fill); blocks 768..887: K/V projection (tail).
__global__ __launch_bounds__(256, 2) void gemm_q_kv(
    const unsigned short* __restrict__ HSb, const unsigned short* __restrict__ Wqb,
    unsigned short* __restrict__ Qb,
    const unsigned short* __restrict__ EHSb, const unsigned short* __restrict__ Wkb,
    const unsigned short* __restrict__ Wvb,
    unsigned short* __restrict__ Ck, unsigned short* __restrict__ Vt) {
  __shared__ unsigned short smem[24576];   // 49152 B: big path 2x(256+128)x32; kv path 2x 128x32
  if (blockIdx.x < 768)
    gemm_big_body<0>(HSb, Wqb, Qb, nullptr, nullptr, nullptr, smem, blockIdx.x, threadIdx.x);
  else
    gemm_kv_body(EHSb, Wkb, Wvb, Ck, Vt, smem, blockIdx.x - 768, threadIdx.x);
}

// ---------------- O-projection GEMM (MODE 1: + bias + residual, fp32 out) ----------------
__global__ __launch_bounds__(256, 2) void gemm_o(
    const unsigned short* __restrict__ Ob, const unsigned short* __restrict__ Wob,
    float* __restrict__ Cf, const float* __restrict__ bias, const float* __restrict__ resid) {
  __shared__ unsigned short smem[24576];
  gemm_big_body<1>(Ob, Wob, nullptr, Cf, bias, resid, smem, blockIdx.x, threadIdx.x);
}

// ---------------- fused cross-component attention ----------------
// grid (64 s-blocks, 24 heads), 256 thr = 4 waves; wave owns 16 s-rows, all 4 components.
// K/V register double-buffered; softmax WITHOUT max-subtraction (|scores| << 88, fp32-exp safe;
// ratio mathematically identical). P masked to 0 for e>=154. P[w] is WAVE-PRIVATE -> no
// __syncthreads anywhere (DS ops are wave-ordered; lgkm drains only). Output: stage wave's
// 16x64 tile in now-free P[w], then 128B-contiguous short8 stores.
__global__ __launch_bounds__(256) void attn_kernel(
    const unsigned short* __restrict__ Qb,   // [4*4096, 1536]
    const unsigned short* __restrict__ Kb,   // [640, 1536]; rows c*154+e (rows>=616 junk, masked)
    const unsigned short* __restrict__ Vt,   // [4][24][64][160]; e>=154 junk, masked via P
    const float* __restrict__ temp,
    unsigned short* __restrict__ Ob) {       // [4*4096, 1536]
  __shared__ unsigned short P[4][4][16][160];  // [wave][c][s][e] bf16 weights (wave-private)
  const int h = blockIdx.y, sb = blockIdx.x;
  const int t = threadIdx.x, w = t >> 6, l = t & 63, lr = l & 15, lg = l >> 4;
  const int s0 = sb * 64 + w * 16;
  const float sc = 1.0f / (temp[0] + 1e-8f);

  short8 qf[4][2];
#pragma unroll
  for (int c = 0; c < 4; ++c)
#pragma unroll
    for (int kt = 0; kt < 2; ++kt)
      qf[c][kt] = *(const short8*)(Qb + (long)(c * 4096 + s0 + lr) * 1536 + h * 64 + kt * 32 + lg * 8);

  short8 kA[4][2], kB[4][2];
  auto loadK = [&](int et, short8 (&k)[4][2]) {
#pragma unroll
    for (int c = 0; c < 4; ++c)
#pragma unroll
      for (int kt = 0; kt < 2; ++kt)
        k[c][kt] = *(const short8*)(Kb + (long)(c * 154 + et * 16 + lr) * 1536 + h * 64 + kt * 32 + lg * 8);
  };

  auto qk_step = [&](int et, short8 (&kc)[4][2], short8 (&kn)[4][2], bool pre) {
    if (pre) loadK(et + 1, kn);               // issue next-tile loads BEFORE dependent MFMAs
    f32x4 sa[4] = {};
#pragma unroll
    for (int c = 0; c < 4; ++c)
#pragma unroll
      for (int kt = 0; kt < 2; ++kt)
        sa[c] = __builtin_amdgcn_mfma_f32_16x16x32_bf16(kc[c][kt], qf[c][kt], sa[c], 0, 0, 0);
    float wv[4][4];
#pragma unroll
    for (int r = 0; r < 4; ++r) {
      float e0 = __expf(sa[0][r] * sc), e1 = __expf(sa[1][r] * sc);
      float e2 = __expf(sa[2][r] * sc), e3 = __expf(sa[3][r] * sc);
      float inv = 1.0f / (e0 + e1 + e2 + e3);
      wv[0][r] = e0 * inv; wv[1][r] = e1 * inv; wv[2][r] = e2 * inv; wv[3][r] = e3 * inv;
    }
#pragma unroll
    for (int c = 0; c < 4; ++c) {
      us4 pk;
#pragma unroll
      for (int r = 0; r < 4; ++r)
        pk[r] = (et * 16 + lg * 4 + r < 154) ? f2bf(wv[c][r]) : (unsigned short)0;
      *(us4*)&P[w][c][lr][et * 16 + lg * 4] = pk;
    }
  };

  loadK(0, kA);
#pragma unroll
  for (int et = 0; et < 10; et += 2) {
    qk_step(et,     kA, kB, true);
    qk_step(et + 1, kB, kA, et + 1 < 9);
  }
  asm volatile("s_waitcnt lgkmcnt(0)" ::: "memory");   // P writes drained (wave-private, no bar)
  __builtin_amdgcn_sched_barrier(0);

  // ---- PV with V-fragment register double-buffer ----
  short8 vA[4], vB[4];
  auto loadV = [&](int c, int ks, short8 (&v)[4]) {
#pragma unroll
    for (int nt = 0; nt < 4; ++nt)
      v[nt] = *(const short8*)(Vt + (long)((c * 24 + h) * 64 + nt * 16 + lr) * 160 + ks * 32 + lg * 8);
  };

  f32x4 o[4][4] = {};
  loadV(0, 0, vA);
#pragma unroll
  for (int p = 0; p < 10; ++p) {
    const int i0 = 2 * p, i1 = 2 * p + 1;
    const int c0 = i0 / 5, k0 = i0 % 5;
    const int c1 = i1 / 5, k1 = i1 % 5;
    loadV(c1, k1, vB);                        // prefetch odd step's V
    short8 pf0 = *(const short8*)&P[w][c0][lr][k0 * 32 + lg * 8];
#pragma unroll
    for (int nt = 0; nt < 4; ++nt)
      o[c0][nt] = __builtin_amdgcn_mfma_f32_16x16x32_bf16(pf0, vA[nt], o[c0][nt], 0, 0, 0);
    if (p < 9) loadV((i1 + 1) / 5, (i1 + 1) % 5, vA);   // prefetch next even step's V
    short8 pf1 = *(const short8*)&P[w][c1][lr][k1 * 32 + lg * 8];
#pragma unroll
    for (int nt = 0; nt < 4; ++nt)
      o[c1][nt] = __builtin_amdgcn_mfma_f32_16x16x32_bf16(pf1, vB[nt], o[c1][nt], 0, 0, 0);
  }

  // ---- coalesced Ob write: stage 16x64 tile in now-free wave-private P[w], 128B chunks ----
  unsigned short* OS = &P[w][0][0][0];        // PV's P reads all retired (consumed by MFMAs)
#pragma unroll
  for (int c = 0; c < 4; ++c) {
#pragma unroll
    for (int nt = 0; nt < 4; ++nt)
#pragma unroll
      for (int r = 0; r < 4; ++r)
        OS[(lg * 4 + r) * 64 + nt * 16 + lr] = f2bf(o[c][nt][r]);
    asm volatile("s_waitcnt lgkmcnt(0)" ::: "memory");  // scalar ds_writes drained
    __builtin_amdgcn_sched_barrier(0);
#pragma unroll
    for (int p = 0; p < 2; ++p) {
      const int flat = p * 512 + l * 8;       // elem index within 16x64 tile
      const int row = flat >> 6, col = flat & 63;
      short8 v = *(const short8*)(OS + flat);
      *(short8*)(Ob + (long)(c * 4096 + s0 + row) * 1536 + h * 64 + col) = v;
    }
  }
}

extern "C" void kernel_launch(void* const* d_in, const int* in_sizes, int n_in,
                              void* d_out, int out_size, void* d_ws, size_t ws_size,
                              hipStream_t stream) {
  (void)in_sizes; (void)n_in; (void)out_size; (void)ws_size;
  const float* HS  = (const float*)d_in[0];
  const float* EHS = (const float*)d_in[1];
  const float* TMP = (const float*)d_in[2];
  const float* Wq  = (const float*)d_in[3];
  const float* Wk  = (const float*)d_in[4];
  const float* Wv  = (const float*)d_in[5];
  const float* Wo  = (const float*)d_in[6];
  const float* bo  = (const float*)d_in[7];

  char* ws = (char*)d_ws;
  size_t off = 0;
  unsigned short* HSb  = (unsigned short*)(ws + off); off += (size_t)16384 * 1536 * 2;  // reused as Ob
  unsigned short* Ob   = HSb;
  unsigned short* EHSb = (unsigned short*)(ws + off); off += (size_t)616 * 1536 * 2;
  unsigned short* Wqb  = (unsigned short*)(ws + off); off += (size_t)1536 * 1536 * 2;
  unsigned short* Wkb  = (unsigned short*)(ws + off); off += (size_t)1536 * 1536 * 2;
  unsigned short* Wvb  = (unsigned short*)(ws + off); off += (size_t)1536 * 1536 * 2;
  unsigned short* Wob  = (unsigned short*)(ws + off); off += (size_t)1536 * 1536 * 2;
  unsigned short* Kb   = (unsigned short*)(ws + off); off += (size_t)640 * 1536 * 2;
  unsigned short* Vt   = (unsigned short*)(ws + off); off += (size_t)4 * 24 * 64 * 160 * 2;
  unsigned short* Qb   = (unsigned short*)d_out;  // bf16 scratch; final GEMM overwrites d_out fully

  cvt_all<<<2048, 256, 0, stream>>>(HS, EHS, Wq, Wk, Wv, Wo,
                                    HSb, EHSb, Wqb, Wkb, Wvb, Wob);

  gemm_q_kv<<<888, 256, 0, stream>>>(HSb, Wqb, Qb, EHSb, Wkb, Wvb, Kb, Vt);

  attn_kernel<<<dim3(64, 24), 256, 0, stream>>>(Qb, Kb, Vt, TMP, Ob);

  gemm_o<<<768, 256, 0, stream>>>(Ob, Wob, (float*)d_out, bo, HS);
}